// Round 1
// baseline (50.747 us; speedup 1.0000x reference)
//
#include <hip/hip_runtime.h>

#define BATCH 16
#define CH    64
#define H     128
#define W     128
#define HO    126
#define WO    126
#define NPIX  (HO * WO)   // 15876

// One block per (b,c) plane. Stage plane in LDS, compute 3x3 window stats
// per output pixel in 4-pixel groups, reduce to a single mean per plane.
__global__ __launch_bounds__(256) void bp_kernel(const float* __restrict__ x,
                                                 float* __restrict__ out) {
    __shared__ float tile[H * W + 8];   // +8 pad so tail-group reads stay in-bounds
    __shared__ float wsum[4];

    const int plane = blockIdx.x;
    const float* src = x + (size_t)plane * (H * W);
    const int tid = threadIdx.x;

    // ---- stage 64 KiB plane into LDS (coalesced float4) ----
    {
        const float4* s4 = (const float4*)src;
        float4* t4 = (float4*)tile;
#pragma unroll
        for (int i = 0; i < 16; ++i)
            t4[tid + 256 * i] = s4[tid + 256 * i];
        if (tid < 8) tile[H * W + tid] = 0.f;
    }
    __syncthreads();

    float acc = 0.f;

    // 32 groups of 4 pixels per output row; 126 rows -> 4032 groups.
    for (int g = tid; g < HO * 32; g += 256) {
        const int y  = g >> 5;
        const int x0 = (g & 31) << 2;
        const int base = y * W + x0;

        // load 3 rows x 6 cols (float4 + float2 per row)
        float r[3][6];
#pragma unroll
        for (int i = 0; i < 3; ++i) {
            const float4 a = *(const float4*)&tile[base + i * W];
            const float2 b = *(const float2*)&tile[base + i * W + 4];
            r[i][0] = a.x; r[i][1] = a.y; r[i][2] = a.z; r[i][3] = a.w;
            r[i][4] = b.x; r[i][5] = b.y;
        }

        // per-column partials shared by the 4 pixels
        float colsum[6], colss[6], colmax[6];
#pragma unroll
        for (int c = 0; c < 6; ++c) {
            colsum[c] = r[0][c] + r[1][c] + r[2][c];
            colss[c]  = r[0][c] * r[0][c] + r[1][c] * r[1][c] + r[2][c] * r[2][c];
            colmax[c] = fmaxf(fmaxf(r[0][c], r[1][c]), r[2][c]);
        }

#pragma unroll
        for (int k = 0; k < 4; ++k) {
            const float ctr = r[1][k + 1];
            const float sum  = colsum[k] + colsum[k + 1] + colsum[k + 2];
            const float ss   = colss[k]  + colss[k + 1]  + colss[k + 2];
            const float wmax = fmaxf(fmaxf(colmax[k], colmax[k + 1]), colmax[k + 2]);

            float d[9];
#pragma unroll
            for (int i = 0; i < 3; ++i)
#pragma unroll
                for (int j = 0; j < 3; ++j)
                    d[i * 3 + j] = r[i][k + j] - ctr;

            float sad = 0.f;
#pragma unroll
            for (int t = 0; t < 9; ++t) sad += fabsf(d[t]);
            const float thr = sad * (1.f / 9.f);

            float bv = 0.f;
#pragma unroll
            for (int t = 0; t < 9; ++t) bv += (d[t] >= thr) ? 1.f : 0.f;

            const float wm  = sum * (1.f / 9.f);
            const float msq = ss * (1.f / 9.f);
            float var = msq - wm * wm;
            var = fmaxf(var, 0.f);
            const float sd = sqrtf(var);

            const float nf = (bv - wm) * (1.f / 255.f);
            const float bn = nf * sd + (1.f - nf) * wmax;

            if (x0 + k < WO) acc += bn;
        }
    }

    // ---- block reduction: wave shuffle, then 4 wave sums in LDS ----
#pragma unroll
    for (int off = 32; off > 0; off >>= 1)
        acc += __shfl_down(acc, off, 64);
    if ((tid & 63) == 0) wsum[tid >> 6] = acc;
    __syncthreads();
    if (tid == 0)
        out[plane] = (wsum[0] + wsum[1] + wsum[2] + wsum[3]) * (1.f / NPIX);
}

extern "C" void kernel_launch(void* const* d_in, const int* in_sizes, int n_in,
                              void* d_out, int out_size, void* d_ws, size_t ws_size,
                              hipStream_t stream) {
    const float* x = (const float*)d_in[0];
    float* out = (float*)d_out;
    bp_kernel<<<dim3(BATCH * CH), dim3(256), 0, stream>>>(x, out);
}

// Round 2
// 44.946 us; speedup vs baseline: 1.1291x; 1.1291x over previous
//
#include <hip/hip_runtime.h>

#define H     128
#define W     128
#define HO    126
#define WO    126
#define NPIX  (HO * WO)          // 15876
#define CROWS 63                 // output rows per chunk
#define TROWS 65                 // staged input rows per chunk (63 + 2 halo)
#define TSZ   (TROWS * W + 8)    // float tile + pad

// f4-block swizzle: toggle bit0 of f4-slot with bit3 -> 16-lane read phases
// cover 8 distinct bank-quads instead of 4.
__device__ __forceinline__ int sw(int j) { return j ^ ((j >> 3) & 1); }

__device__ __forceinline__ float fast_sqrtf(float x) {
#if __has_builtin(__builtin_amdgcn_sqrtf)
    return __builtin_amdgcn_sqrtf(x);
#else
    return sqrtf(x);
#endif
}

// One block per (b,c) plane; two sequential 63-row chunks staged in LDS.
__global__ __launch_bounds__(256, 4) void bp_kernel(const float* __restrict__ x,
                                                    float* __restrict__ out) {
    __shared__ float tile[TSZ];
    __shared__ float wsum[4];

    const int plane = blockIdx.x;
    const float4* src4 = (const float4*)(x + (size_t)plane * (H * W));
    const int tid = threadIdx.x;

    float acc = 0.f;

    for (int c = 0; c < 2; ++c) {
        const int R = c * CROWS;              // first staged input row

        // ---- stage 65 rows (swizzled f4 slots), coalesced ----
        float4* t4 = (float4*)tile;
        for (int i = tid; i < TROWS * (W / 4); i += 256) {
            const int row = i >> 5, j = i & 31;
            t4[row * 32 + sw(j)] = src4[(R + row) * 32 + j];
        }
        if (tid < 8) tile[TROWS * W + tid] = 0.f;
        __syncthreads();

        // ---- 63 rows x 16 groups of 8 pixels ----
        for (int g = tid; g < CROWS * 16; g += 256) {
            const int y  = g >> 4;
            const int xq = g & 15;
            const int x0 = xq << 3;
            const int jb = xq << 1;
            const int s0 = sw(jb) << 2;
            const int s1 = sw(jb + 1) << 2;
            const int s2 = sw(jb + 2) << 2;   // jb=30 -> 32 (spills to next row / pad; feeds invalid px only)

            float r[3][10];
#pragma unroll
            for (int dr = 0; dr < 3; ++dr) {
                const int base = (y + dr) * W;
                const float4 a = *(const float4*)&tile[base + s0];
                const float4 b = *(const float4*)&tile[base + s1];
                const float2 e = *(const float2*)&tile[base + s2];
                r[dr][0] = a.x; r[dr][1] = a.y; r[dr][2] = a.z; r[dr][3] = a.w;
                r[dr][4] = b.x; r[dr][5] = b.y; r[dr][6] = b.z; r[dr][7] = b.w;
                r[dr][8] = e.x; r[dr][9] = e.y;
            }

            float colsum[10], colss[10], colmax[10];
#pragma unroll
            for (int cc = 0; cc < 10; ++cc) {
                colsum[cc] = r[0][cc] + r[1][cc] + r[2][cc];
                colss[cc]  = r[0][cc]*r[0][cc] + r[1][cc]*r[1][cc] + r[2][cc]*r[2][cc];
                colmax[cc] = fmaxf(fmaxf(r[0][cc], r[1][cc]), r[2][cc]);
            }

#pragma unroll
            for (int k = 0; k < 8; ++k) {
                const float ctr  = r[1][k + 1];
                const float sum  = colsum[k] + colsum[k + 1] + colsum[k + 2];
                const float ss   = colss[k]  + colss[k + 1]  + colss[k + 2];
                const float wmax = fmaxf(fmaxf(colmax[k], colmax[k + 1]), colmax[k + 2]);

                float sad = 0.f;                     // center's |d|=0 skipped
#pragma unroll
                for (int i = 0; i < 3; ++i)
#pragma unroll
                    for (int j = 0; j < 3; ++j)
                        if (!(i == 1 && j == 1))
                            sad += fabsf(r[i][k + j] - ctr);
                const float thr = sad * (1.f / 9.f);
                const float cth = ctr + thr;

                float bv = (thr <= 0.f) ? 1.f : 0.f; // center: (0 >= thr)
#pragma unroll
                for (int i = 0; i < 3; ++i)
#pragma unroll
                    for (int j = 0; j < 3; ++j)
                        if (!(i == 1 && j == 1))
                            bv += (r[i][k + j] >= cth) ? 1.f : 0.f;

                const float wm  = sum * (1.f / 9.f);
                const float msq = ss * (1.f / 9.f);
                const float sd  = fast_sqrtf(fmaxf(msq - wm * wm, 0.f));
                const float nf  = (bv - wm) * (1.f / 255.f);
                const float bn  = wmax + nf * (sd - wmax);

                acc += (x0 + k < WO) ? bn : 0.f;
            }
        }
        if (c == 0) __syncthreads();   // protect tile before restage
    }

    // ---- block reduction ----
#pragma unroll
    for (int off = 32; off > 0; off >>= 1)
        acc += __shfl_down(acc, off, 64);
    if ((tid & 63) == 0) wsum[tid >> 6] = acc;
    __syncthreads();
    if (tid == 0)
        out[plane] = (wsum[0] + wsum[1] + wsum[2] + wsum[3]) * (1.f / NPIX);
}

extern "C" void kernel_launch(void* const* d_in, const int* in_sizes, int n_in,
                              void* d_out, int out_size, void* d_ws, size_t ws_size,
                              hipStream_t stream) {
    const float* x = (const float*)d_in[0];
    float* out = (float*)d_out;
    bp_kernel<<<dim3(16 * 64), dim3(256), 0, stream>>>(x, out);
}